// Round 12
// baseline (241.973 us; speedup 1.0000x reference)
//
#include <hip/hip_runtime.h>
#include <hip/hip_fp16.h>
#include <math.h>

#define N_NODES 50000
#define N_EDGES 800000
#define D 64
#define NB 196            // dst buckets of 256 nodes (b = dst>>8)
#define CAP_B 6144        // per-bucket binned capacity (mean 4082, +32 sigma)
#define SLOT_CAP 64       // per-node CSR slot capacity (mean deg 16)
#define EB 2048           // edges per binA block (8 per thread)
#define BINA_BLOCKS ((N_EDGES + EB - 1) / EB)   // 391
#define GEMM_BLOCKS ((N_NODES + 63) / 64)       // 782

// ---------------------------------------------------------------------------
// zero the 196 bucket cursors
// ---------------------------------------------------------------------------
__global__ void k_zero(int* __restrict__ bcur) {
    int t = threadIdx.x;
    if (t < NB) bcur[t] = 0;
}

// ---------------------------------------------------------------------------
// Pass A: bin edges by dst>>8 into 196 buckets. Entry PACKED to 4B:
// (src<<8)|(dst&255) — src<50000 needs 17 bits, local dst 8 bits.
// ---------------------------------------------------------------------------
__global__ __launch_bounds__(256) void k_binA(const int* __restrict__ src,
                                              const int* __restrict__ dst,
                                              int* __restrict__ bcur,
                                              unsigned* __restrict__ binned) {
    __shared__ int hist[NB];
    __shared__ int base[NB];
    int tid = threadIdx.x;
    int e0 = blockIdx.x * EB;

    unsigned pk[8];
    int eb[8];
    bool ev[8];
    #pragma unroll
    for (int k = 0; k < 8; ++k) {
        int e = e0 + k * 256 + tid;
        ev[k] = (e < N_EDGES);
        int s = ev[k] ? src[e] : 0;
        int d = ev[k] ? dst[e] : 0;
        eb[k] = d >> 8;
        pk[k] = ((unsigned)s << 8) | (unsigned)(d & 255);
    }
    if (tid < NB) hist[tid] = 0;
    __syncthreads();
    #pragma unroll
    for (int k = 0; k < 8; ++k) if (ev[k]) atomicAdd(&hist[eb[k]], 1);
    __syncthreads();
    if (tid < NB) {
        base[tid] = atomicAdd(&bcur[tid], hist[tid]);
        hist[tid] = 0;                      // reuse as rank counter
    }
    __syncthreads();
    #pragma unroll
    for (int k = 0; k < 8; ++k) {
        if (ev[k]) {
            int r = atomicAdd(&hist[eb[k]], 1);
            int pos = base[eb[k]] + r;
            if (pos < CAP_B)
                binned[(size_t)eb[k] * CAP_B + pos] = pk[k];
        }
    }
}

// ---------------------------------------------------------------------------
// Pass B: one block per bucket, LDS cursors, 64KB L2-resident csr window.
// Final cursor value IS the in-degree.
// ---------------------------------------------------------------------------
__global__ __launch_bounds__(256) void k_binB(const int* __restrict__ bcur,
                                              const unsigned* __restrict__ binned,
                                              int* __restrict__ csr,
                                              int* __restrict__ cnt) {
    __shared__ int cur[256];
    int b = blockIdx.x;
    int tid = threadIdx.x;
    cur[tid] = 0;
    __syncthreads();
    int bn = bcur[b];
    if (bn > CAP_B) bn = CAP_B;
    const unsigned* bp = binned + (size_t)b * CAP_B;
    for (int i = tid; i < bn; i += 256) {
        unsigned e = bp[i];
        int dl = (int)(e & 255u);
        int s  = (int)(e >> 8);
        int c = atomicAdd(&cur[dl], 1);
        if (c < SLOT_CAP) {
            int node = (b << 8) + dl;
            csr[((size_t)node << 6) + c] = s;
        }
    }
    __syncthreads();
    int node = (b << 8) + tid;
    if (node < N_NODES) {
        int c = cur[tid];
        cnt[node] = (c > SLOT_CAP) ? SLOT_CAP : c;
    }
}

// ---------------------------------------------------------------------------
// GEMM: hWs[row,:] = (h[row,:] @ W) * rsqrt(cnt[row]+1), fp16 out.
// Operands LDS-resident (R7 lesson: global-staged W regs -> VGPR=256 spill).
// h tile stored FP16 in LDS (8.7 KB): total 24.7 KB -> 6 blocks/CU.
// ---------------------------------------------------------------------------
__global__ __launch_bounds__(256) void k_gemm(const float* __restrict__ h, int hstride,
                                              const float* __restrict__ W,
                                              const int* __restrict__ cnt,
                                              __half* __restrict__ hWh) {
    __shared__ float Ws[64][64];          // 16 KB
    __shared__ __half2 hs2[64 * 34];      // 8.7 KB, row stride 34 half2
    int tid = threadIdx.x;
    int row0 = blockIdx.x * 64;

    const float4* W4 = (const float4*)W;
    for (int i = tid; i < 64 * 16; i += 256) {
        float4 w = W4[i];
        *(float4*)&Ws[i >> 4][(i & 15) << 2] = w;
    }
    for (int i = tid; i < 64 * 16; i += 256) {
        int r = i >> 4, c4 = (i & 15) << 2;
        int gr = row0 + r;
        float4 hv = make_float4(0.f, 0.f, 0.f, 0.f);
        if (gr < N_NODES) hv = *(const float4*)&h[(size_t)gr * hstride + c4];
        __half2 p01 = __floats2half2_rn(hv.x, hv.y);
        __half2 p23 = __floats2half2_rn(hv.z, hv.w);
        uint2 st;
        st.x = *(unsigned*)&p01;
        st.y = *(unsigned*)&p23;
        *(uint2*)&hs2[r * 34 + (c4 >> 1)] = st;
    }
    __syncthreads();

    int c0 = (tid & 15) << 2;    // output cols c0..c0+3
    int r0 = (tid >> 4) << 2;    // output rows r0..r0+3
    float4 a0 = make_float4(0.f, 0.f, 0.f, 0.f);
    float4 a1 = a0, a2 = a0, a3 = a0;

    #pragma unroll 2
    for (int k0 = 0; k0 < 64; k0 += 4) {
        float4 w0 = *(const float4*)&Ws[k0 + 0][c0];
        float4 w1 = *(const float4*)&Ws[k0 + 1][c0];
        float4 w2 = *(const float4*)&Ws[k0 + 2][c0];
        float4 w3 = *(const float4*)&Ws[k0 + 3][c0];
#define LOAD_H(i, HV)                                                   \
        float4 HV;                                                      \
        {                                                               \
            uint2 hp = *(const uint2*)&hs2[(r0 + i) * 34 + (k0 >> 1)];  \
            float2 f01 = __half22float2(*(const __half2*)&hp.x);        \
            float2 f23 = __half22float2(*(const __half2*)&hp.y);        \
            HV = make_float4(f01.x, f01.y, f23.x, f23.y);               \
        }
        LOAD_H(0, h0)
        LOAD_H(1, h1)
        LOAD_H(2, h2)
        LOAD_H(3, h3)
#undef LOAD_H
#define GEMM_ROW(A, H)                                            \
        A.x += H.x*w0.x + H.y*w1.x + H.z*w2.x + H.w*w3.x;         \
        A.y += H.x*w0.y + H.y*w1.y + H.z*w2.y + H.w*w3.y;         \
        A.z += H.x*w0.z + H.y*w1.z + H.z*w2.z + H.w*w3.z;         \
        A.w += H.x*w0.w + H.y*w1.w + H.z*w2.w + H.w*w3.w;
        GEMM_ROW(a0, h0)
        GEMM_ROW(a1, h1)
        GEMM_ROW(a2, h2)
        GEMM_ROW(a3, h3)
#undef GEMM_ROW
    }

    #pragma unroll
    for (int i = 0; i < 4; ++i) {
        int gr = row0 + r0 + i;
        if (gr < N_NODES) {
            float4 v = (i == 0) ? a0 : (i == 1) ? a1 : (i == 2) ? a2 : a3;
            float dn = rsqrtf((float)cnt[gr] + 1.0f);
            __half2 p01 = __floats2half2_rn(v.x * dn, v.y * dn);
            __half2 p23 = __floats2half2_rn(v.z * dn, v.w * dn);
            uint2 st;
            st.x = *(unsigned*)&p01;
            st.y = *(unsigned*)&p23;
            *(uint2*)&hWh[((size_t)gr << 6) + c0] = st;
        }
    }
}

// ---------------------------------------------------------------------------
// Gather v4: full wave per node; CSR row loaded once (coalesced, one lane
// each) and distributed via __shfl. R10 BUG FIX: the edge loop trip count is
// now WAVE-UNIFORM (nIter = ceil(n/16)), so every __shfl executes with all
// 64 lanes active (shfl from an inactive lane is undefined on CDNA — that
// was R10's absmax=2.4). Validity is predicated AFTER the shfl; the
// predicate chain contains no cross-lane ops.
// ---------------------------------------------------------------------------
__global__ __launch_bounds__(256) void k_gather(const uint2* __restrict__ hW4,  // [N][16]
                                                const int* __restrict__ csr,
                                                const int* __restrict__ cnt,
                                                const float* __restrict__ bias,
                                                float* __restrict__ out, int col_off) {
    int gid = blockIdx.x * blockDim.x + threadIdx.x;
    int node = gid >> 6;
    if (node >= N_NODES) return;
    int lane = threadIdx.x & 63;
    int fq = lane & 15;          // feature quad: features 4*fq..4*fq+3
    int g  = lane >> 4;          // edge group 0..3
    int n = cnt[node];           // wave-uniform
    const int* row = csr + ((size_t)node << 6);

    int myidx = (lane < n) ? row[lane] : 0;          // whole row, one load
    uint2 sv = hW4[((size_t)node << 4) + fq];        // self row, issued early

    float a0 = 0.f, a1 = 0.f, a2 = 0.f, a3 = 0.f;
#define ACC_EDGE(S)                                                  \
    {                                                                \
        uint2 v = hW4[((size_t)(S) << 4) + fq];                      \
        float2 f0 = __half22float2(*(const __half2*)&v.x);           \
        float2 f1 = __half22float2(*(const __half2*)&v.y);           \
        a0 += f0.x; a1 += f0.y; a2 += f1.x; a3 += f1.y;              \
    }
    int nIter = (n + 15) >> 4;           // wave-uniform trip count (<=4)
    for (int it = 0; it < nIter; ++it) {
        int jb = (it << 4) + (g << 2);   // group's 4 consecutive edges
        int s0 = __shfl(myidx, jb + 0, 64);   // all lanes active here
        int s1 = __shfl(myidx, jb + 1, 64);
        int s2 = __shfl(myidx, jb + 2, 64);
        int s3 = __shfl(myidx, jb + 3, 64);
        int rem = n - jb;
        if (rem >= 4) {
            ACC_EDGE(s0) ACC_EDGE(s1) ACC_EDGE(s2) ACC_EDGE(s3)
        } else if (rem > 0) {
            ACC_EDGE(s0)
            if (rem > 1) ACC_EDGE(s1)
            if (rem > 2) ACC_EDGE(s2)
        }
    }
#undef ACC_EDGE

    // combine the 4 edge-groups
    a0 += __shfl_xor(a0, 16, 64);
    a1 += __shfl_xor(a1, 16, 64);
    a2 += __shfl_xor(a2, 16, 64);
    a3 += __shfl_xor(a3, 16, 64);
    a0 += __shfl_xor(a0, 32, 64);
    a1 += __shfl_xor(a1, 32, 64);
    a2 += __shfl_xor(a2, 32, 64);
    a3 += __shfl_xor(a3, 32, 64);

    if (g == 0) {
        float2 s0 = __half22float2(*(const __half2*)&sv.x);
        float2 s1 = __half22float2(*(const __half2*)&sv.y);
        float dn = rsqrtf((float)n + 1.0f);
        float4 bb = *(const float4*)&bias[fq << 2];
        float o0 = bb.x + dn * (s0.x + a0);
        float o1 = bb.y + dn * (s0.y + a1);
        float o2 = bb.z + dn * (s1.x + a2);
        float o3 = bb.w + dn * (s1.y + a3);
        o0 = (o0 > 0.f) ? o0 : expm1f(o0);
        o1 = (o1 > 0.f) ? o1 : expm1f(o1);
        o2 = (o2 > 0.f) ? o2 : expm1f(o2);
        o3 = (o3 > 0.f) ? o3 : expm1f(o3);
        *(float4*)&out[(size_t)node * (3 * D) + col_off + (fq << 2)] =
            make_float4(o0, o1, o2, o3);
    }
}

extern "C" void kernel_launch(void* const* d_in, const int* in_sizes, int n_in,
                              void* d_out, int out_size, void* d_ws, size_t ws_size,
                              hipStream_t stream) {
    const float* x   = (const float*)d_in[0];
    const int*   ei  = (const int*)d_in[1];
    const int*   src = ei;
    const int*   dst = ei + N_EDGES;
    const float* W[3] = {(const float*)d_in[2], (const float*)d_in[4], (const float*)d_in[6]};
    const float* b[3] = {(const float*)d_in[3], (const float*)d_in[5], (const float*)d_in[7]};
    float* out = (float*)d_out;

    // workspace layout
    char* ws = (char*)d_ws;
    unsigned* binned = (unsigned*)ws;            ws += (size_t)NB * CAP_B * 4;
    int*    bcur   = (int*)ws;                   ws += 256 * 4;
    int*    cnt    = (int*)ws;                   ws += N_NODES * 4;
    int*    csr    = (int*)ws;                   ws += (size_t)N_NODES * SLOT_CAP * 4;
    __half* hWh    = (__half*)ws;                // N*D halves

    // CSR build: zero cursors, bin, scatter-within-bucket
    k_zero<<<1, 256, 0, stream>>>(bcur);
    k_binA<<<BINA_BLOCKS, 256, 0, stream>>>(src, dst, bcur, binned);
    k_binB<<<NB, 256, 0, stream>>>(bcur, binned, csr, cnt);

    long long gthreads = (long long)N_NODES * 64;
    int gather_grid = (int)((gthreads + 255) / 256);   // 12500

    const float* hin = x;
    int hstride = D;
    for (int l = 0; l < 3; ++l) {
        k_gemm<<<GEMM_BLOCKS, 256, 0, stream>>>(hin, hstride, W[l], cnt, hWh);
        k_gather<<<gather_grid, 256, 0, stream>>>(
            (const uint2*)hWh, csr, cnt, b[l], out, l * D);
        hin = out + l * D;
        hstride = 3 * D;
    }
}